// Round 2
// baseline (352.571 us; speedup 1.0000x reference)
//
#include <hip/hip_runtime.h>
#include <stdint.h>

#define BB 8
#define NPT 8192
#define SPT 2048
#define C1D 128
#define C2D 256
#define CIN 384
#define HD 256

typedef __attribute__((ext_vector_type(8))) short bf16x8;
typedef __attribute__((ext_vector_type(4))) float f32x4;

__device__ __forceinline__ unsigned short f2b(float f){
  unsigned int u = __float_as_uint(f);
  u += 0x7fffu + ((u >> 16) & 1u);   // RNE; inputs finite
  return (unsigned short)(u >> 16);
}

// ---------------- f32 -> bf16 convert (for W1/W2 prep) ----------------
__global__ __launch_bounds__(256) void cvt_bf16_kernel(const float* __restrict__ src,
                                                       unsigned short* __restrict__ dst, int n){
  int i = blockIdx.x * 256 + threadIdx.x;
  if (i < n) dst[i] = f2b(src[i]);
}

// ---------------- max |coor2| * 3 (single block) ----------------
__global__ __launch_bounds__(1024) void kmax_kernel(const float* __restrict__ c2,
                                                    float* __restrict__ outp, int n){
  __shared__ float red[16];
  float m = 0.f;
  for (int i = threadIdx.x; i < n; i += 1024) m = fmaxf(m, fabsf(c2[i]));
  #pragma unroll
  for (int o = 32; o > 0; o >>= 1) m = fmaxf(m, __shfl_xor(m, o));
  if ((threadIdx.x & 63) == 0) red[threadIdx.x >> 6] = m;
  __syncthreads();
  if (threadIdx.x == 0){
    float mm = red[0];
    for (int i = 1; i < 16; i++) mm = fmaxf(mm, red[i]);
    outp[0] = mm * 3.0f;
  }
}

// ---------------- [B,C,N] f32 -> [B,N,C(dstStride)] bf16 tile transpose ----------------
__global__ __launch_bounds__(256) void transpose_cn(const float* __restrict__ src,
    unsigned short* __restrict__ dst, int Cdim, int Ndim, int dstStride){
  __shared__ unsigned short t[32][33];
  int b = blockIdx.z;
  int n0 = blockIdx.x * 32, c0 = blockIdx.y * 32;
  int tx = threadIdx.x, ty = threadIdx.y;
  const float* s = src + (size_t)b * Cdim * Ndim;
  unsigned short* d = dst + (size_t)b * Ndim * dstStride;
  #pragma unroll
  for (int i = 0; i < 4; i++)
    t[ty + i*8][tx] = f2b(s[(size_t)(c0 + ty + i*8) * Ndim + n0 + tx]);
  __syncthreads();
  #pragma unroll
  for (int i = 0; i < 4; i++)
    d[(size_t)(n0 + ty + i*8) * dstStride + c0 + tx] = t[tx][ty + i*8];
}

// ---------------- 3-NN + inverse-distance weights (all f32) ----------------
__global__ __launch_bounds__(256) void knn_kernel(const float* __restrict__ coor1,
    const float* __restrict__ coor2, const unsigned char* __restrict__ pad,
    const float* __restrict__ bigptr, float* __restrict__ w3, int* __restrict__ i3){
  __shared__ float4 sc[SPT];            // x,y,z,|c|^2  (32 KB)
  int b = blockIdx.y;
  float big = bigptr[0];
  const float* cb = coor2 + b * 3 * SPT;
  const unsigned char* pb = pad + (size_t)b * SPT;
  for (int s = threadIdx.x; s < SPT; s += 256){
    float x = cb[s], y = cb[SPT + s], z = cb[2*SPT + s];
    if (pb[s]) { x = big; y = big; z = big; }
    float n2 = __fadd_rn(__fadd_rn(__fmul_rn(x,x), __fmul_rn(y,y)), __fmul_rn(z,z));
    sc[s] = make_float4(x, y, z, n2);
  }
  __syncthreads();
  int n = blockIdx.x * 256 + threadIdx.x;
  const float* ca = coor1 + b * 3 * NPT;
  float x1 = ca[n], y1 = ca[NPT + n], z1 = ca[2*NPT + n];
  float n1 = __fadd_rn(__fadd_rn(__fmul_rn(x1,x1), __fmul_rn(y1,y1)), __fmul_rn(z1,z1));
  float v0 = 3.4e38f, v1 = 3.4e38f, v2 = 3.4e38f;
  int j0 = 0, j1 = 0, j2 = 0;
  #pragma unroll 4
  for (int s = 0; s < SPT; s++){
    float4 q = sc[s];
    // non-contracted f32 to track numpy's rounding (selection must match)
    float dot = __fadd_rn(__fadd_rn(__fmul_rn(x1,q.x), __fmul_rn(y1,q.y)), __fmul_rn(z1,q.z));
    float d = __fsub_rn(__fadd_rn(n1, q.w), __fmul_rn(2.0f, dot));
    bool l0 = d < v0, l1 = d < v1, l2 = d < v2;   // strict < keeps earliest index on ties
    v2 = l1 ? v1 : (l2 ? d : v2);  j2 = l1 ? j1 : (l2 ? s : j2);
    v1 = l0 ? v0 : (l1 ? d : v1);  j1 = l0 ? j0 : (l1 ? s : j1);
    v0 = l0 ? d : v0;              j0 = l0 ? s : j0;
  }
  float r0 = 1.0f / fmaxf(v0, 1e-8f);
  float r1 = 1.0f / fmaxf(v1, 1e-8f);
  float r2 = 1.0f / fmaxf(v2, 1e-8f);
  float rs = (r0 + r1) + r2;
  size_t m = (size_t)b * NPT + n;
  w3[m*3+0] = r0 / rs; w3[m*3+1] = r1 / rs; w3[m*3+2] = r2 / rs;
  i3[m*3+0] = j0; i3[m*3+1] = j1; i3[m*3+2] = j2;
}

// ---------------- gather + weighted sum -> xpm[:,128:384] bf16 (wave per point) ----------------
__global__ __launch_bounds__(256) void interp_kernel(const unsigned short* __restrict__ f2t,
    const float* __restrict__ w3, const int* __restrict__ i3, unsigned short* __restrict__ xpm){
  int m = blockIdx.x * 4 + (threadIdx.x >> 6);
  int lane = threadIdx.x & 63;
  int b = m >> 13;
  int s0 = i3[m*3+0], s1 = i3[m*3+1], s2 = i3[m*3+2];
  float w0 = w3[m*3+0], w1 = w3[m*3+1], w2 = w3[m*3+2];
  const ushort4 a = *(const ushort4*)(f2t + (size_t)(b*SPT + s0) * C2D + lane*4);
  const ushort4 c = *(const ushort4*)(f2t + (size_t)(b*SPT + s1) * C2D + lane*4);
  const ushort4 e = *(const ushort4*)(f2t + (size_t)(b*SPT + s2) * C2D + lane*4);
  #define B2F(u) __uint_as_float(((unsigned int)(u)) << 16)
  ushort4 o;
  o.x = f2b(w0*B2F(a.x) + w1*B2F(c.x) + w2*B2F(e.x));
  o.y = f2b(w0*B2F(a.y) + w1*B2F(c.y) + w2*B2F(e.y));
  o.z = f2b(w0*B2F(a.z) + w1*B2F(c.z) + w2*B2F(e.z));
  o.w = f2b(w0*B2F(a.w) + w1*B2F(c.w) + w2*B2F(e.w));
  *(ushort4*)(xpm + (size_t)m * CIN + C1D + lane*4) = o;
}

// ---------------- GEMM1 (K=384, bf16 MFMA) + bias + LN + relu -> Hg bf16 [m][256] ----------------
// block: 256 thr = 4 waves, 64 points; wave w owns points m0+w*16+(lane&15), all 256 outs.
__global__ __launch_bounds__(256) void mlp1_kernel(const unsigned short* __restrict__ xpm,
    const unsigned short* __restrict__ Wg, const float* __restrict__ bg,
    const float* __restrict__ gg, const float* __restrict__ beg,
    unsigned short* __restrict__ Hg){
  __shared__ __align__(16) unsigned short Ws[256*40];   // W chunk [256 o][32 k], pad->40
  __shared__ __align__(16) unsigned short Xs[64*40];    // X chunk [64 m][32 k]
  __shared__ __align__(16) unsigned short Hb[64*136];   // store bounce, 128 cols + pad
  __shared__ float sB[256], sG[256], sBe[256];
  int tid = threadIdx.x;
  int m0 = blockIdx.x * 64;
  sB[tid] = bg[tid]; sG[tid] = gg[tid]; sBe[tid] = beg[tid];
  int w = tid >> 6, lane = tid & 63, col = lane & 15, quad = lane >> 4;
  f32x4 acc[16];
  #pragma unroll
  for (int i = 0; i < 16; i++) acc[i] = (f32x4)0.0f;
  for (int kb = 0; kb < CIN; kb += 32){
    __syncthreads();
    {
      const int4* s4 = (const int4*)(Wg + (size_t)tid * CIN + kb);
      int4* d4 = (int4*)(Ws + tid * 40);
      #pragma unroll
      for (int i = 0; i < 4; i++) d4[i] = s4[i];
    }
    {
      int mr = tid >> 2, part = tid & 3;
      *(int4*)(Xs + mr*40 + part*8) = *(const int4*)(xpm + (size_t)(m0 + mr) * CIN + kb + part*8);
    }
    __syncthreads();
    bf16x8 bfrag = *(const bf16x8*)(Xs + (w*16 + col)*40 + quad*8);
    #pragma unroll
    for (int ot = 0; ot < 16; ot++){
      bf16x8 afrag = *(const bf16x8*)(Ws + (ot*16 + col)*40 + quad*8);
      acc[ot] = __builtin_amdgcn_mfma_f32_16x16x32_bf16(afrag, bfrag, acc[ot], 0, 0, 0);
    }
  }
  float s1 = 0.f, s2 = 0.f;
  #pragma unroll
  for (int ot = 0; ot < 16; ot++)
    #pragma unroll
    for (int r = 0; r < 4; r++){
      int o = ot*16 + quad*4 + r;
      float v = acc[ot][r] + sB[o];
      acc[ot][r] = v;
      s1 += v; s2 += v*v;
    }
  s1 += __shfl_xor(s1, 16); s1 += __shfl_xor(s1, 32);
  s2 += __shfl_xor(s2, 16); s2 += __shfl_xor(s2, 32);
  float mu = s1 * (1.f/256.f);
  float rinv = rsqrtf(s2 * (1.f/256.f) - mu*mu + 1e-5f);
  for (int half = 0; half < 2; half++){
    __syncthreads();
    #pragma unroll
    for (int ot8 = 0; ot8 < 8; ot8++){
      int ot = half*8 + ot8;
      int ob = ot*16 + quad*4;
      ushort4 hv;
      hv.x = f2b(fmaxf((acc[ot][0] - mu) * rinv * sG[ob+0] + sBe[ob+0], 0.f));
      hv.y = f2b(fmaxf((acc[ot][1] - mu) * rinv * sG[ob+1] + sBe[ob+1], 0.f));
      hv.z = f2b(fmaxf((acc[ot][2] - mu) * rinv * sG[ob+2] + sBe[ob+2], 0.f));
      hv.w = f2b(fmaxf((acc[ot][3] - mu) * rinv * sG[ob+3] + sBe[ob+3], 0.f));
      *(ushort4*)(Hb + (w*16 + col)*136 + ot8*16 + quad*4) = hv;
    }
    __syncthreads();
    int mr = tid >> 2, part = tid & 3;
    #pragma unroll
    for (int r = 0; r < 4; r++){
      int piece = part*4 + r;
      *(int4*)(Hg + (size_t)(m0 + mr)*HD + half*128 + piece*8) = *(const int4*)(Hb + mr*136 + piece*8);
    }
  }
}

// ---------------- GEMM2 (K=256, bf16 MFMA) + bias + LN + relu -> out f32 [B,256,N] ----------------
__global__ __launch_bounds__(256) void mlp2_kernel(const unsigned short* __restrict__ Hg,
    const unsigned short* __restrict__ Wg, const float* __restrict__ bg,
    const float* __restrict__ gg, const float* __restrict__ beg,
    float* __restrict__ outg){
  __shared__ __align__(16) unsigned short Ws[256*40];
  __shared__ __align__(16) unsigned short Xs[64*40];
  __shared__ float sB[256], sG[256], sBe[256];
  int tid = threadIdx.x;
  int m0 = blockIdx.x * 64;
  int b = m0 >> 13, n0 = m0 & (NPT - 1);
  sB[tid] = bg[tid]; sG[tid] = gg[tid]; sBe[tid] = beg[tid];
  int w = tid >> 6, lane = tid & 63, col = lane & 15, quad = lane >> 4;
  f32x4 acc[16];
  #pragma unroll
  for (int i = 0; i < 16; i++) acc[i] = (f32x4)0.0f;
  for (int kb = 0; kb < HD; kb += 32){
    __syncthreads();
    {
      const int4* s4 = (const int4*)(Wg + (size_t)tid * HD + kb);
      int4* d4 = (int4*)(Ws + tid * 40);
      #pragma unroll
      for (int i = 0; i < 4; i++) d4[i] = s4[i];
    }
    {
      int mr = tid >> 2, part = tid & 3;
      *(int4*)(Xs + mr*40 + part*8) = *(const int4*)(Hg + (size_t)(m0 + mr) * HD + kb + part*8);
    }
    __syncthreads();
    bf16x8 bfrag = *(const bf16x8*)(Xs + (w*16 + col)*40 + quad*8);
    #pragma unroll
    for (int ot = 0; ot < 16; ot++){
      bf16x8 afrag = *(const bf16x8*)(Ws + (ot*16 + col)*40 + quad*8);
      acc[ot] = __builtin_amdgcn_mfma_f32_16x16x32_bf16(afrag, bfrag, acc[ot], 0, 0, 0);
    }
  }
  float s1 = 0.f, s2 = 0.f;
  #pragma unroll
  for (int ot = 0; ot < 16; ot++)
    #pragma unroll
    for (int r = 0; r < 4; r++){
      int o = ot*16 + quad*4 + r;
      float v = acc[ot][r] + sB[o];
      acc[ot][r] = v;
      s1 += v; s2 += v*v;
    }
  s1 += __shfl_xor(s1, 16); s1 += __shfl_xor(s1, 32);
  s2 += __shfl_xor(s2, 16); s2 += __shfl_xor(s2, 32);
  float mu = s1 * (1.f/256.f);
  float rinv = rsqrtf(s2 * (1.f/256.f) - mu*mu + 1e-5f);
  size_t obase = (size_t)b * HD * NPT + n0 + w*16 + col;
  #pragma unroll
  for (int ot = 0; ot < 16; ot++)
    #pragma unroll
    for (int r = 0; r < 4; r++){
      int o = ot*16 + quad*4 + r;
      float v = (acc[ot][r] - mu) * rinv * sG[o] + sBe[o];
      outg[obase + (size_t)o * NPT] = fmaxf(v, 0.f);
    }
}

extern "C" void kernel_launch(void* const* d_in, const int* in_sizes, int n_in,
                              void* d_out, int out_size, void* d_ws, size_t ws_size,
                              hipStream_t stream){
  const float* coor1 = (const float*)d_in[0];
  const float* coor2 = (const float*)d_in[1];
  const float* fea1  = (const float*)d_in[2];
  const float* fea2  = (const float*)d_in[3];
  const unsigned char* pad = (const unsigned char*)d_in[4];
  const float* W1  = (const float*)d_in[5];
  const float* b1  = (const float*)d_in[6];
  const float* g1  = (const float*)d_in[7];
  const float* be1 = (const float*)d_in[8];
  const float* W2  = (const float*)d_in[9];
  const float* b2  = (const float*)d_in[10];
  const float* g2  = (const float*)d_in[11];
  const float* be2 = (const float*)d_in[12];
  float* out = (float*)d_out;

  // ws layout (~94.2 MB): bigmax | w3 | i3 | W1b | W2b | f2t | xpm | Hg
  char* ws = (char*)d_ws;
  float* bigmax        = (float*)(ws + 0);
  float* w3            = (float*)(ws + 256);
  int*   i3            = (int*)  (ws + 786688);
  unsigned short* W1b  = (unsigned short*)(ws + 1573120);
  unsigned short* W2b  = (unsigned short*)(ws + 1769728);
  unsigned short* f2t  = (unsigned short*)(ws + 1900800);
  unsigned short* xpm  = (unsigned short*)(ws + 10289408);
  unsigned short* Hg   = (unsigned short*)(ws + 60621056);

  cvt_bf16_kernel<<<(HD*CIN + 255)/256, 256, 0, stream>>>(W1, W1b, HD*CIN);
  cvt_bf16_kernel<<<(HD*HD + 255)/256, 256, 0, stream>>>(W2, W2b, HD*HD);
  kmax_kernel<<<1, 1024, 0, stream>>>(coor2, bigmax, BB*3*SPT);
  dim3 tb(32, 8);
  transpose_cn<<<dim3(SPT/32, C2D/32, BB), tb, 0, stream>>>(fea2, f2t, C2D, SPT, C2D);
  transpose_cn<<<dim3(NPT/32, C1D/32, BB), tb, 0, stream>>>(fea1, xpm, C1D, NPT, CIN);
  knn_kernel<<<dim3(NPT/256, BB), 256, 0, stream>>>(coor1, coor2, pad, bigmax, w3, i3);
  interp_kernel<<<BB*NPT/4, 256, 0, stream>>>(f2t, w3, i3, xpm);
  mlp1_kernel<<<BB*NPT/64, 256, 0, stream>>>(xpm, W1b, b1, g1, be1, Hg);
  mlp2_kernel<<<BB*NPT/64, 256, 0, stream>>>(Hg, W2b, b2, g2, be2, out);
}

// Round 3
// 315.096 us; speedup vs baseline: 1.1189x; 1.1189x over previous
//
#include <hip/hip_runtime.h>
#include <stdint.h>

#define BB 8
#define NPT 8192
#define SPT 2048
#define C1D 128
#define C2D 256
#define CIN 384
#define HD 256
#define SPLIT 4
#define SC (SPT/SPLIT)   // 512 source points per chunk

typedef __attribute__((ext_vector_type(8))) short bf16x8;
typedef __attribute__((ext_vector_type(4))) float f32x4;

__device__ __forceinline__ unsigned short f2b(float f){
  unsigned int u = __float_as_uint(f);
  u += 0x7fffu + ((u >> 16) & 1u);   // RNE; inputs finite
  return (unsigned short)(u >> 16);
}

// ---------------- f32 -> bf16 convert (for W1/W2 prep) ----------------
__global__ __launch_bounds__(256) void cvt_bf16_kernel(const float* __restrict__ src,
                                                       unsigned short* __restrict__ dst, int n){
  int i = blockIdx.x * 256 + threadIdx.x;
  if (i < n) dst[i] = f2b(src[i]);
}

// ---------------- max |coor2| * 3 (single block) ----------------
__global__ __launch_bounds__(1024) void kmax_kernel(const float* __restrict__ c2,
                                                    float* __restrict__ outp, int n){
  __shared__ float red[16];
  float m = 0.f;
  for (int i = threadIdx.x; i < n; i += 1024) m = fmaxf(m, fabsf(c2[i]));
  #pragma unroll
  for (int o = 32; o > 0; o >>= 1) m = fmaxf(m, __shfl_xor(m, o));
  if ((threadIdx.x & 63) == 0) red[threadIdx.x >> 6] = m;
  __syncthreads();
  if (threadIdx.x == 0){
    float mm = red[0];
    for (int i = 1; i < 16; i++) mm = fmaxf(mm, red[i]);
    outp[0] = mm * 3.0f;
  }
}

// ---------------- [B,C,N] f32 -> [B,N,C(dstStride)] bf16 tile transpose ----------------
__global__ __launch_bounds__(256) void transpose_cn(const float* __restrict__ src,
    unsigned short* __restrict__ dst, int Cdim, int Ndim, int dstStride){
  __shared__ unsigned short t[32][33];
  int b = blockIdx.z;
  int n0 = blockIdx.x * 32, c0 = blockIdx.y * 32;
  int tx = threadIdx.x, ty = threadIdx.y;
  const float* s = src + (size_t)b * Cdim * Ndim;
  unsigned short* d = dst + (size_t)b * Ndim * dstStride;
  #pragma unroll
  for (int i = 0; i < 4; i++)
    t[ty + i*8][tx] = f2b(s[(size_t)(c0 + ty + i*8) * Ndim + n0 + tx]);
  __syncthreads();
  #pragma unroll
  for (int i = 0; i < 4; i++)
    d[(size_t)(n0 + ty + i*8) * dstStride + c0 + tx] = t[tx][ty + i*8];
}

// ---------------- 3-NN partial scan over one S-chunk (occupancy: 1024 blocks) ----------------
__global__ __launch_bounds__(256) void knn_part_kernel(const float* __restrict__ coor1,
    const float* __restrict__ coor2, const unsigned char* __restrict__ pad,
    const float* __restrict__ bigptr, float* __restrict__ cv, int* __restrict__ cj){
  __shared__ float4 sc[SC];             // x,y,z,|c|^2  (8 KB)
  int b = blockIdx.y, c = blockIdx.z;
  int s0c = c * SC;
  float big = bigptr[0];
  const float* cb = coor2 + b * 3 * SPT;
  const unsigned char* pb = pad + (size_t)b * SPT;
  for (int s = threadIdx.x; s < SC; s += 256){
    int ss = s0c + s;
    float x = cb[ss], y = cb[SPT + ss], z = cb[2*SPT + ss];
    if (pb[ss]) { x = big; y = big; z = big; }
    float n2 = __fadd_rn(__fadd_rn(__fmul_rn(x,x), __fmul_rn(y,y)), __fmul_rn(z,z));
    sc[s] = make_float4(x, y, z, n2);
  }
  __syncthreads();
  int n = blockIdx.x * 256 + threadIdx.x;
  const float* ca = coor1 + b * 3 * NPT;
  float x1 = ca[n], y1 = ca[NPT + n], z1 = ca[2*NPT + n];
  float n1 = __fadd_rn(__fadd_rn(__fmul_rn(x1,x1), __fmul_rn(y1,y1)), __fmul_rn(z1,z1));
  float v0 = 3.4e38f, v1 = 3.4e38f, v2 = 3.4e38f;
  int j0 = 0, j1 = 0, j2 = 0;
  #pragma unroll 4
  for (int s = 0; s < SC; s++){
    float4 q = sc[s];
    // non-contracted f32 to track numpy's rounding (selection must match)
    float dot = __fadd_rn(__fadd_rn(__fmul_rn(x1,q.x), __fmul_rn(y1,q.y)), __fmul_rn(z1,q.z));
    float d = __fsub_rn(__fadd_rn(n1, q.w), __fmul_rn(2.0f, dot));
    bool l0 = d < v0, l1 = d < v1, l2 = d < v2;   // strict < keeps earliest index on ties
    v2 = l1 ? v1 : (l2 ? d : v2);  j2 = l1 ? j1 : (l2 ? s : j2);
    v1 = l0 ? v0 : (l1 ? d : v1);  j1 = l0 ? j0 : (l1 ? s : j1);
    v0 = l0 ? d : v0;              j0 = l0 ? s : j0;
  }
  size_t m = (size_t)b * NPT + n;
  size_t base = (m * SPLIT + c) * 3;
  cv[base+0] = v0; cv[base+1] = v1; cv[base+2] = v2;
  cj[base+0] = s0c + j0; cj[base+1] = s0c + j1; cj[base+2] = s0c + j2;
}

// ---------------- merge SPLIT x top-3 -> global top-3 + weights ----------------
__global__ __launch_bounds__(256) void knn_merge_kernel(const float* __restrict__ cv,
    const int* __restrict__ cj, float* __restrict__ w3, int* __restrict__ i3){
  size_t m = (size_t)blockIdx.x * 256 + threadIdx.x;
  float v0 = 3.4e38f, v1 = 3.4e38f, v2 = 3.4e38f;
  int j0 = 0, j1 = 0, j2 = 0;
  // chunk-ascending insert order + strict < == global sequential scan tie-order
  #pragma unroll
  for (int c = 0; c < SPLIT; c++){
    #pragma unroll
    for (int k = 0; k < 3; k++){
      float d = cv[(m * SPLIT + c) * 3 + k];
      int j   = cj[(m * SPLIT + c) * 3 + k];
      bool l0 = d < v0, l1 = d < v1, l2 = d < v2;
      v2 = l1 ? v1 : (l2 ? d : v2);  j2 = l1 ? j1 : (l2 ? j : j2);
      v1 = l0 ? v0 : (l1 ? d : v1);  j1 = l0 ? j0 : (l1 ? j : j1);
      v0 = l0 ? d : v0;              j0 = l0 ? j : j0;
    }
  }
  float r0 = 1.0f / fmaxf(v0, 1e-8f);
  float r1 = 1.0f / fmaxf(v1, 1e-8f);
  float r2 = 1.0f / fmaxf(v2, 1e-8f);
  float rs = (r0 + r1) + r2;
  w3[m*3+0] = r0 / rs; w3[m*3+1] = r1 / rs; w3[m*3+2] = r2 / rs;
  i3[m*3+0] = j0; i3[m*3+1] = j1; i3[m*3+2] = j2;
}

// ---------------- gather + weighted sum -> xpm[:,128:384] bf16 (wave per point) ----------------
__global__ __launch_bounds__(256) void interp_kernel(const unsigned short* __restrict__ f2t,
    const float* __restrict__ w3, const int* __restrict__ i3, unsigned short* __restrict__ xpm){
  int m = blockIdx.x * 4 + (threadIdx.x >> 6);
  int lane = threadIdx.x & 63;
  int b = m >> 13;
  int s0 = i3[m*3+0], s1 = i3[m*3+1], s2 = i3[m*3+2];
  float w0 = w3[m*3+0], w1 = w3[m*3+1], w2 = w3[m*3+2];
  const ushort4 a = *(const ushort4*)(f2t + (size_t)(b*SPT + s0) * C2D + lane*4);
  const ushort4 c = *(const ushort4*)(f2t + (size_t)(b*SPT + s1) * C2D + lane*4);
  const ushort4 e = *(const ushort4*)(f2t + (size_t)(b*SPT + s2) * C2D + lane*4);
  #define B2F(u) __uint_as_float(((unsigned int)(u)) << 16)
  ushort4 o;
  o.x = f2b(w0*B2F(a.x) + w1*B2F(c.x) + w2*B2F(e.x));
  o.y = f2b(w0*B2F(a.y) + w1*B2F(c.y) + w2*B2F(e.y));
  o.z = f2b(w0*B2F(a.z) + w1*B2F(c.z) + w2*B2F(e.z));
  o.w = f2b(w0*B2F(a.w) + w1*B2F(c.w) + w2*B2F(e.w));
  *(ushort4*)(xpm + (size_t)m * CIN + C1D + lane*4) = o;
}

// ---------------- GEMM1 (K=384, bf16 MFMA) + bias + LN + relu -> Hg bf16 [m][256] ----------------
// block: 256 thr = 4 waves, 64 points; wave w owns points m0+w*16+(lane&15), all 256 outs.
__global__ __launch_bounds__(256) void mlp1_kernel(const unsigned short* __restrict__ xpm,
    const unsigned short* __restrict__ Wg, const float* __restrict__ bg,
    const float* __restrict__ gg, const float* __restrict__ beg,
    unsigned short* __restrict__ Hg){
  __shared__ __align__(16) unsigned short Ws[256*40];   // W chunk [256 o][32 k], pad->40
  __shared__ __align__(16) unsigned short Xs[64*40];    // X chunk [64 m][32 k]
  __shared__ __align__(16) unsigned short Hb[64*136];   // store bounce, 128 cols + pad
  __shared__ float sB[256], sG[256], sBe[256];
  int tid = threadIdx.x;
  int m0 = blockIdx.x * 64;
  sB[tid] = bg[tid]; sG[tid] = gg[tid]; sBe[tid] = beg[tid];
  int w = tid >> 6, lane = tid & 63, col = lane & 15, quad = lane >> 4;
  f32x4 acc[16];
  #pragma unroll
  for (int i = 0; i < 16; i++) acc[i] = (f32x4)0.0f;
  for (int kb = 0; kb < CIN; kb += 32){
    __syncthreads();
    {
      const int4* s4 = (const int4*)(Wg + (size_t)tid * CIN + kb);
      int4* d4 = (int4*)(Ws + tid * 40);
      #pragma unroll
      for (int i = 0; i < 4; i++) d4[i] = s4[i];
    }
    {
      int mr = tid >> 2, part = tid & 3;
      *(int4*)(Xs + mr*40 + part*8) = *(const int4*)(xpm + (size_t)(m0 + mr) * CIN + kb + part*8);
    }
    __syncthreads();
    bf16x8 bfrag = *(const bf16x8*)(Xs + (w*16 + col)*40 + quad*8);
    #pragma unroll
    for (int ot = 0; ot < 16; ot++){
      bf16x8 afrag = *(const bf16x8*)(Ws + (ot*16 + col)*40 + quad*8);
      acc[ot] = __builtin_amdgcn_mfma_f32_16x16x32_bf16(afrag, bfrag, acc[ot], 0, 0, 0);
    }
  }
  float s1 = 0.f, s2 = 0.f;
  #pragma unroll
  for (int ot = 0; ot < 16; ot++)
    #pragma unroll
    for (int r = 0; r < 4; r++){
      int o = ot*16 + quad*4 + r;
      float v = acc[ot][r] + sB[o];
      acc[ot][r] = v;
      s1 += v; s2 += v*v;
    }
  s1 += __shfl_xor(s1, 16); s1 += __shfl_xor(s1, 32);
  s2 += __shfl_xor(s2, 16); s2 += __shfl_xor(s2, 32);
  float mu = s1 * (1.f/256.f);
  float rinv = rsqrtf(s2 * (1.f/256.f) - mu*mu + 1e-5f);
  for (int half = 0; half < 2; half++){
    __syncthreads();
    #pragma unroll
    for (int ot8 = 0; ot8 < 8; ot8++){
      int ot = half*8 + ot8;
      int ob = ot*16 + quad*4;
      ushort4 hv;
      hv.x = f2b(fmaxf((acc[ot][0] - mu) * rinv * sG[ob+0] + sBe[ob+0], 0.f));
      hv.y = f2b(fmaxf((acc[ot][1] - mu) * rinv * sG[ob+1] + sBe[ob+1], 0.f));
      hv.z = f2b(fmaxf((acc[ot][2] - mu) * rinv * sG[ob+2] + sBe[ob+2], 0.f));
      hv.w = f2b(fmaxf((acc[ot][3] - mu) * rinv * sG[ob+3] + sBe[ob+3], 0.f));
      *(ushort4*)(Hb + (w*16 + col)*136 + ot8*16 + quad*4) = hv;
    }
    __syncthreads();
    int mr = tid >> 2, part = tid & 3;
    #pragma unroll
    for (int r = 0; r < 4; r++){
      int piece = part*4 + r;
      *(int4*)(Hg + (size_t)(m0 + mr)*HD + half*128 + piece*8) = *(const int4*)(Hb + mr*136 + piece*8);
    }
  }
}

// ---------------- GEMM2 (K=256, bf16 MFMA) + bias + LN + relu -> out f32 [B,256,N] ----------------
__global__ __launch_bounds__(256) void mlp2_kernel(const unsigned short* __restrict__ Hg,
    const unsigned short* __restrict__ Wg, const float* __restrict__ bg,
    const float* __restrict__ gg, const float* __restrict__ beg,
    float* __restrict__ outg){
  __shared__ __align__(16) unsigned short Ws[256*40];
  __shared__ __align__(16) unsigned short Xs[64*40];
  __shared__ float sB[256], sG[256], sBe[256];
  int tid = threadIdx.x;
  int m0 = blockIdx.x * 64;
  int b = m0 >> 13, n0 = m0 & (NPT - 1);
  sB[tid] = bg[tid]; sG[tid] = gg[tid]; sBe[tid] = beg[tid];
  int w = tid >> 6, lane = tid & 63, col = lane & 15, quad = lane >> 4;
  f32x4 acc[16];
  #pragma unroll
  for (int i = 0; i < 16; i++) acc[i] = (f32x4)0.0f;
  for (int kb = 0; kb < HD; kb += 32){
    __syncthreads();
    {
      const int4* s4 = (const int4*)(Wg + (size_t)tid * HD + kb);
      int4* d4 = (int4*)(Ws + tid * 40);
      #pragma unroll
      for (int i = 0; i < 4; i++) d4[i] = s4[i];
    }
    {
      int mr = tid >> 2, part = tid & 3;
      *(int4*)(Xs + mr*40 + part*8) = *(const int4*)(Hg + (size_t)(m0 + mr) * HD + kb + part*8);
    }
    __syncthreads();
    bf16x8 bfrag = *(const bf16x8*)(Xs + (w*16 + col)*40 + quad*8);
    #pragma unroll
    for (int ot = 0; ot < 16; ot++){
      bf16x8 afrag = *(const bf16x8*)(Ws + (ot*16 + col)*40 + quad*8);
      acc[ot] = __builtin_amdgcn_mfma_f32_16x16x32_bf16(afrag, bfrag, acc[ot], 0, 0, 0);
    }
  }
  float s1 = 0.f, s2 = 0.f;
  #pragma unroll
  for (int ot = 0; ot < 16; ot++)
    #pragma unroll
    for (int r = 0; r < 4; r++){
      int o = ot*16 + quad*4 + r;
      float v = acc[ot][r] + sB[o];
      acc[ot][r] = v;
      s1 += v; s2 += v*v;
    }
  s1 += __shfl_xor(s1, 16); s1 += __shfl_xor(s1, 32);
  s2 += __shfl_xor(s2, 16); s2 += __shfl_xor(s2, 32);
  float mu = s1 * (1.f/256.f);
  float rinv = rsqrtf(s2 * (1.f/256.f) - mu*mu + 1e-5f);
  size_t obase = (size_t)b * HD * NPT + n0 + w*16 + col;
  #pragma unroll
  for (int ot = 0; ot < 16; ot++)
    #pragma unroll
    for (int r = 0; r < 4; r++){
      int o = ot*16 + quad*4 + r;
      float v = (acc[ot][r] - mu) * rinv * sG[o] + sBe[o];
      outg[obase + (size_t)o * NPT] = fmaxf(v, 0.f);
    }
}

extern "C" void kernel_launch(void* const* d_in, const int* in_sizes, int n_in,
                              void* d_out, int out_size, void* d_ws, size_t ws_size,
                              hipStream_t stream){
  const float* coor1 = (const float*)d_in[0];
  const float* coor2 = (const float*)d_in[1];
  const float* fea1  = (const float*)d_in[2];
  const float* fea2  = (const float*)d_in[3];
  const unsigned char* pad = (const unsigned char*)d_in[4];
  const float* W1  = (const float*)d_in[5];
  const float* b1  = (const float*)d_in[6];
  const float* g1  = (const float*)d_in[7];
  const float* be1 = (const float*)d_in[8];
  const float* W2  = (const float*)d_in[9];
  const float* b2  = (const float*)d_in[10];
  const float* g2  = (const float*)d_in[11];
  const float* be2 = (const float*)d_in[12];
  float* out = (float*)d_out;

  // ws layout (~94.2 MB, same footprint as round 2):
  // bigmax | w3 | i3 | W1b | W2b | f2t | xpm | Hg
  // cv/cj alias the Hg region (Hg written only later, single stream => safe)
  char* ws = (char*)d_ws;
  float* bigmax        = (float*)(ws + 0);
  float* w3            = (float*)(ws + 256);
  int*   i3            = (int*)  (ws + 786688);
  unsigned short* W1b  = (unsigned short*)(ws + 1573120);
  unsigned short* W2b  = (unsigned short*)(ws + 1769728);
  unsigned short* f2t  = (unsigned short*)(ws + 1900800);
  unsigned short* xpm  = (unsigned short*)(ws + 10289408);
  unsigned short* Hg   = (unsigned short*)(ws + 60621056);
  float* cv            = (float*)(ws + 60621056);            // aliases Hg[0 : 3.1MB)
  int*   cj            = (int*)  (ws + 60621056 + 3145728);  // aliases Hg[3.1 : 6.3MB)

  cvt_bf16_kernel<<<(HD*CIN + 255)/256, 256, 0, stream>>>(W1, W1b, HD*CIN);
  cvt_bf16_kernel<<<(HD*HD + 255)/256, 256, 0, stream>>>(W2, W2b, HD*HD);
  kmax_kernel<<<1, 1024, 0, stream>>>(coor2, bigmax, BB*3*SPT);
  dim3 tb(32, 8);
  transpose_cn<<<dim3(SPT/32, C2D/32, BB), tb, 0, stream>>>(fea2, f2t, C2D, SPT, C2D);
  transpose_cn<<<dim3(NPT/32, C1D/32, BB), tb, 0, stream>>>(fea1, xpm, C1D, NPT, CIN);
  knn_part_kernel<<<dim3(NPT/256, BB, SPLIT), 256, 0, stream>>>(coor1, coor2, pad, bigmax, cv, cj);
  knn_merge_kernel<<<BB*NPT/256, 256, 0, stream>>>(cv, cj, w3, i3);
  interp_kernel<<<BB*NPT/4, 256, 0, stream>>>(f2t, w3, i3, xpm);
  mlp1_kernel<<<BB*NPT/64, 256, 0, stream>>>(xpm, W1b, b1, g1, be1, Hg);
  mlp2_kernel<<<BB*NPT/64, 256, 0, stream>>>(Hg, W2b, b2, g2, be2, out);
}

// Round 4
// 288.601 us; speedup vs baseline: 1.2217x; 1.0918x over previous
//
#include <hip/hip_runtime.h>
#include <stdint.h>

#define BB 8
#define NPT 8192
#define SPT 2048
#define C1D 128
#define C2D 256
#define CIN 384
#define HD 256
#define SPLIT 8
#define SC (SPT/SPLIT)   // 256 source points per chunk

typedef __attribute__((ext_vector_type(8))) short bf16x8;
typedef __attribute__((ext_vector_type(4))) float f32x4;

__device__ __forceinline__ unsigned short f2b(float f){
  unsigned int u = __float_as_uint(f);
  u += 0x7fffu + ((u >> 16) & 1u);   // RNE; inputs finite
  return (unsigned short)(u >> 16);
}

// ---------------- f32 -> bf16 convert (for W1/W2 prep) ----------------
__global__ __launch_bounds__(256) void cvt_bf16_kernel(const float* __restrict__ src,
                                                       unsigned short* __restrict__ dst, int n){
  int i = blockIdx.x * 256 + threadIdx.x;
  if (i < n) dst[i] = f2b(src[i]);
}

// ---------------- [B,C,N] f32 -> [B,N,C(dstStride)] bf16 tile transpose ----------------
__global__ __launch_bounds__(256) void transpose_cn(const float* __restrict__ src,
    unsigned short* __restrict__ dst, int Cdim, int Ndim, int dstStride){
  __shared__ unsigned short t[32][33];
  int b = blockIdx.z;
  int n0 = blockIdx.x * 32, c0 = blockIdx.y * 32;
  int tx = threadIdx.x, ty = threadIdx.y;
  const float* s = src + (size_t)b * Cdim * Ndim;
  unsigned short* d = dst + (size_t)b * Ndim * dstStride;
  #pragma unroll
  for (int i = 0; i < 4; i++)
    t[ty + i*8][tx] = f2b(s[(size_t)(c0 + ty + i*8) * Ndim + n0 + tx]);
  __syncthreads();
  #pragma unroll
  for (int i = 0; i < 4; i++)
    d[(size_t)(n0 + ty + i*8) * dstStride + c0 + tx] = t[tx][ty + i*8];
}

// ---------------- 3-NN partial scan over one S-chunk ----------------
// 16 VALU/pair: 7 distance (fma trick is bit-exact: fl(2*dot)==2*dot) + 3 cmp
// + 5 cndmask (indices) + min/med3/med3 (values; provably == sorted insert).
// big = 1e19 const: padding is all-false in this problem; for any padding,
// 1e19^2*3 ~ 3e38 (finite, no overflow) still excludes padded points.
__global__ __launch_bounds__(256) void knn_part_kernel(const float* __restrict__ coor1,
    const float* __restrict__ coor2, const unsigned char* __restrict__ pad,
    float* __restrict__ cv, int* __restrict__ cj){
  __shared__ float4 sc[SC];             // x,y,z,|c|^2  (4 KB)
  int b = blockIdx.y, c = blockIdx.z;
  int s0c = c * SC;
  const float* cb = coor2 + b * 3 * SPT;
  const unsigned char* pb = pad + (size_t)b * SPT;
  {
    int s = threadIdx.x;               // SC == blockDim.x == 256
    int ss = s0c + s;
    float x = cb[ss], y = cb[SPT + ss], z = cb[2*SPT + ss];
    if (pb[ss]) { x = 1e19f; y = 1e19f; z = 1e19f; }
    float n2 = __fadd_rn(__fadd_rn(__fmul_rn(x,x), __fmul_rn(y,y)), __fmul_rn(z,z));
    sc[s] = make_float4(x, y, z, n2);
  }
  __syncthreads();
  int n = blockIdx.x * 256 + threadIdx.x;
  const float* ca = coor1 + b * 3 * NPT;
  float x1 = ca[n], y1 = ca[NPT + n], z1 = ca[2*NPT + n];
  float n1 = __fadd_rn(__fadd_rn(__fmul_rn(x1,x1), __fmul_rn(y1,y1)), __fmul_rn(z1,z1));
  float v0 = 3.4e38f, v1 = 3.4e38f, v2 = 3.4e38f;
  int j0 = 0, j1 = 0, j2 = 0;
  #pragma unroll 4
  for (int s = 0; s < SC; s++){
    float4 q = sc[s];
    // non-contracted mul/add dot to track numpy's rounding (selection must match)
    float dot = __fadd_rn(__fadd_rn(__fmul_rn(x1,q.x), __fmul_rn(y1,q.y)), __fmul_rn(z1,q.z));
    float npn = __fadd_rn(n1, q.w);
    float d = __builtin_fmaf(-2.0f, dot, npn);   // == fl(npn - fl(2*dot)) bit-exactly
    bool l0 = d < v0, l1 = d < v1, l2 = d < v2;  // strict < keeps earliest index on ties
    j2 = l1 ? j1 : (l2 ? s : j2);
    j1 = l0 ? j0 : (l1 ? s : j1);
    j0 = l0 ? s  : j0;
    float nv2 = __builtin_amdgcn_fmed3f(v1, v2, d);
    float nv1 = __builtin_amdgcn_fmed3f(v0, v1, d);
    v0 = fminf(v0, d); v1 = nv1; v2 = nv2;
  }
  size_t m = (size_t)b * NPT + n;
  size_t base = (m * SPLIT + c) * 3;
  cv[base+0] = v0; cv[base+1] = v1; cv[base+2] = v2;
  cj[base+0] = s0c + j0; cj[base+1] = s0c + j1; cj[base+2] = s0c + j2;
}

// ---------------- merge SPLIT x top-3 -> global top-3 + weights ----------------
__global__ __launch_bounds__(256) void knn_merge_kernel(const float* __restrict__ cv,
    const int* __restrict__ cj, float* __restrict__ w3, int* __restrict__ i3){
  size_t m = (size_t)blockIdx.x * 256 + threadIdx.x;
  float v0 = 3.4e38f, v1 = 3.4e38f, v2 = 3.4e38f;
  int j0 = 0, j1 = 0, j2 = 0;
  // chunk-ascending insert order + strict < == global sequential scan tie-order
  #pragma unroll
  for (int c = 0; c < SPLIT; c++){
    #pragma unroll
    for (int k = 0; k < 3; k++){
      float d = cv[(m * SPLIT + c) * 3 + k];
      int j   = cj[(m * SPLIT + c) * 3 + k];
      bool l0 = d < v0, l1 = d < v1, l2 = d < v2;
      j2 = l1 ? j1 : (l2 ? j : j2);
      j1 = l0 ? j0 : (l1 ? j : j1);
      j0 = l0 ? j  : j0;
      float nv2 = __builtin_amdgcn_fmed3f(v1, v2, d);
      float nv1 = __builtin_amdgcn_fmed3f(v0, v1, d);
      v0 = fminf(v0, d); v1 = nv1; v2 = nv2;
    }
  }
  float r0 = 1.0f / fmaxf(v0, 1e-8f);
  float r1 = 1.0f / fmaxf(v1, 1e-8f);
  float r2 = 1.0f / fmaxf(v2, 1e-8f);
  float rs = (r0 + r1) + r2;
  w3[m*3+0] = r0 / rs; w3[m*3+1] = r1 / rs; w3[m*3+2] = r2 / rs;
  i3[m*3+0] = j0; i3[m*3+1] = j1; i3[m*3+2] = j2;
}

// ---------------- gather + weighted sum -> xpm[:,128:384] bf16 (wave per point) ----------------
__global__ __launch_bounds__(256) void interp_kernel(const unsigned short* __restrict__ f2t,
    const float* __restrict__ w3, const int* __restrict__ i3, unsigned short* __restrict__ xpm){
  int m = blockIdx.x * 4 + (threadIdx.x >> 6);
  int lane = threadIdx.x & 63;
  int b = m >> 13;
  int s0 = i3[m*3+0], s1 = i3[m*3+1], s2 = i3[m*3+2];
  float w0 = w3[m*3+0], w1 = w3[m*3+1], w2 = w3[m*3+2];
  const ushort4 a = *(const ushort4*)(f2t + (size_t)(b*SPT + s0) * C2D + lane*4);
  const ushort4 c = *(const ushort4*)(f2t + (size_t)(b*SPT + s1) * C2D + lane*4);
  const ushort4 e = *(const ushort4*)(f2t + (size_t)(b*SPT + s2) * C2D + lane*4);
  #define B2F(u) __uint_as_float(((unsigned int)(u)) << 16)
  ushort4 o;
  o.x = f2b(w0*B2F(a.x) + w1*B2F(c.x) + w2*B2F(e.x));
  o.y = f2b(w0*B2F(a.y) + w1*B2F(c.y) + w2*B2F(e.y));
  o.z = f2b(w0*B2F(a.z) + w1*B2F(c.z) + w2*B2F(e.z));
  o.w = f2b(w0*B2F(a.w) + w1*B2F(c.w) + w2*B2F(e.w));
  *(ushort4*)(xpm + (size_t)m * CIN + C1D + lane*4) = o;
}

// ---------------- GEMM1 (K=384, bf16 MFMA) + bias + LN + relu -> Hg bf16 [m][256] ----------------
// block: 256 thr = 4 waves, 64 points; wave w owns points m0+w*16+(lane&15), all 256 outs.
__global__ __launch_bounds__(256) void mlp1_kernel(const unsigned short* __restrict__ xpm,
    const unsigned short* __restrict__ Wg, const float* __restrict__ bg,
    const float* __restrict__ gg, const float* __restrict__ beg,
    unsigned short* __restrict__ Hg){
  __shared__ __align__(16) unsigned short Ws[256*40];   // W chunk [256 o][32 k], pad->40
  __shared__ __align__(16) unsigned short Xs[64*40];    // X chunk [64 m][32 k]
  __shared__ __align__(16) unsigned short Hb[64*136];   // store bounce, 128 cols + pad
  __shared__ float sB[256], sG[256], sBe[256];
  int tid = threadIdx.x;
  int m0 = blockIdx.x * 64;
  sB[tid] = bg[tid]; sG[tid] = gg[tid]; sBe[tid] = beg[tid];
  int w = tid >> 6, lane = tid & 63, col = lane & 15, quad = lane >> 4;
  f32x4 acc[16];
  #pragma unroll
  for (int i = 0; i < 16; i++) acc[i] = (f32x4)0.0f;
  for (int kb = 0; kb < CIN; kb += 32){
    __syncthreads();
    {
      const int4* s4 = (const int4*)(Wg + (size_t)tid * CIN + kb);
      int4* d4 = (int4*)(Ws + tid * 40);
      #pragma unroll
      for (int i = 0; i < 4; i++) d4[i] = s4[i];
    }
    {
      int mr = tid >> 2, part = tid & 3;
      *(int4*)(Xs + mr*40 + part*8) = *(const int4*)(xpm + (size_t)(m0 + mr) * CIN + kb + part*8);
    }
    __syncthreads();
    bf16x8 bfrag = *(const bf16x8*)(Xs + (w*16 + col)*40 + quad*8);
    #pragma unroll
    for (int ot = 0; ot < 16; ot++){
      bf16x8 afrag = *(const bf16x8*)(Ws + (ot*16 + col)*40 + quad*8);
      acc[ot] = __builtin_amdgcn_mfma_f32_16x16x32_bf16(afrag, bfrag, acc[ot], 0, 0, 0);
    }
  }
  float s1 = 0.f, s2 = 0.f;
  #pragma unroll
  for (int ot = 0; ot < 16; ot++)
    #pragma unroll
    for (int r = 0; r < 4; r++){
      int o = ot*16 + quad*4 + r;
      float v = acc[ot][r] + sB[o];
      acc[ot][r] = v;
      s1 += v; s2 += v*v;
    }
  s1 += __shfl_xor(s1, 16); s1 += __shfl_xor(s1, 32);
  s2 += __shfl_xor(s2, 16); s2 += __shfl_xor(s2, 32);
  float mu = s1 * (1.f/256.f);
  float rinv = rsqrtf(s2 * (1.f/256.f) - mu*mu + 1e-5f);
  for (int half = 0; half < 2; half++){
    __syncthreads();
    #pragma unroll
    for (int ot8 = 0; ot8 < 8; ot8++){
      int ot = half*8 + ot8;
      int ob = ot*16 + quad*4;
      ushort4 hv;
      hv.x = f2b(fmaxf((acc[ot][0] - mu) * rinv * sG[ob+0] + sBe[ob+0], 0.f));
      hv.y = f2b(fmaxf((acc[ot][1] - mu) * rinv * sG[ob+1] + sBe[ob+1], 0.f));
      hv.z = f2b(fmaxf((acc[ot][2] - mu) * rinv * sG[ob+2] + sBe[ob+2], 0.f));
      hv.w = f2b(fmaxf((acc[ot][3] - mu) * rinv * sG[ob+3] + sBe[ob+3], 0.f));
      *(ushort4*)(Hb + (w*16 + col)*136 + ot8*16 + quad*4) = hv;
    }
    __syncthreads();
    int mr = tid >> 2, part = tid & 3;
    #pragma unroll
    for (int r = 0; r < 4; r++){
      int piece = part*4 + r;
      *(int4*)(Hg + (size_t)(m0 + mr)*HD + half*128 + piece*8) = *(const int4*)(Hb + mr*136 + piece*8);
    }
  }
}

// ---------------- GEMM2 (K=256, bf16 MFMA) + bias + LN + relu -> out f32 [B,256,N] ----------------
__global__ __launch_bounds__(256) void mlp2_kernel(const unsigned short* __restrict__ Hg,
    const unsigned short* __restrict__ Wg, const float* __restrict__ bg,
    const float* __restrict__ gg, const float* __restrict__ beg,
    float* __restrict__ outg){
  __shared__ __align__(16) unsigned short Ws[256*40];
  __shared__ __align__(16) unsigned short Xs[64*40];
  __shared__ float sB[256], sG[256], sBe[256];
  int tid = threadIdx.x;
  int m0 = blockIdx.x * 64;
  int b = m0 >> 13, n0 = m0 & (NPT - 1);
  sB[tid] = bg[tid]; sG[tid] = gg[tid]; sBe[tid] = beg[tid];
  int w = tid >> 6, lane = tid & 63, col = lane & 15, quad = lane >> 4;
  f32x4 acc[16];
  #pragma unroll
  for (int i = 0; i < 16; i++) acc[i] = (f32x4)0.0f;
  for (int kb = 0; kb < HD; kb += 32){
    __syncthreads();
    {
      const int4* s4 = (const int4*)(Wg + (size_t)tid * HD + kb);
      int4* d4 = (int4*)(Ws + tid * 40);
      #pragma unroll
      for (int i = 0; i < 4; i++) d4[i] = s4[i];
    }
    {
      int mr = tid >> 2, part = tid & 3;
      *(int4*)(Xs + mr*40 + part*8) = *(const int4*)(Hg + (size_t)(m0 + mr) * HD + kb + part*8);
    }
    __syncthreads();
    bf16x8 bfrag = *(const bf16x8*)(Xs + (w*16 + col)*40 + quad*8);
    #pragma unroll
    for (int ot = 0; ot < 16; ot++){
      bf16x8 afrag = *(const bf16x8*)(Ws + (ot*16 + col)*40 + quad*8);
      acc[ot] = __builtin_amdgcn_mfma_f32_16x16x32_bf16(afrag, bfrag, acc[ot], 0, 0, 0);
    }
  }
  float s1 = 0.f, s2 = 0.f;
  #pragma unroll
  for (int ot = 0; ot < 16; ot++)
    #pragma unroll
    for (int r = 0; r < 4; r++){
      int o = ot*16 + quad*4 + r;
      float v = acc[ot][r] + sB[o];
      acc[ot][r] = v;
      s1 += v; s2 += v*v;
    }
  s1 += __shfl_xor(s1, 16); s1 += __shfl_xor(s1, 32);
  s2 += __shfl_xor(s2, 16); s2 += __shfl_xor(s2, 32);
  float mu = s1 * (1.f/256.f);
  float rinv = rsqrtf(s2 * (1.f/256.f) - mu*mu + 1e-5f);
  size_t obase = (size_t)b * HD * NPT + n0 + w*16 + col;
  #pragma unroll
  for (int ot = 0; ot < 16; ot++)
    #pragma unroll
    for (int r = 0; r < 4; r++){
      int o = ot*16 + quad*4 + r;
      float v = (acc[ot][r] - mu) * rinv * sG[o] + sBe[o];
      outg[obase + (size_t)o * NPT] = fmaxf(v, 0.f);
    }
}

extern "C" void kernel_launch(void* const* d_in, const int* in_sizes, int n_in,
                              void* d_out, int out_size, void* d_ws, size_t ws_size,
                              hipStream_t stream){
  const float* coor1 = (const float*)d_in[0];
  const float* coor2 = (const float*)d_in[1];
  const float* fea1  = (const float*)d_in[2];
  const float* fea2  = (const float*)d_in[3];
  const unsigned char* pad = (const unsigned char*)d_in[4];
  const float* W1  = (const float*)d_in[5];
  const float* b1  = (const float*)d_in[6];
  const float* g1  = (const float*)d_in[7];
  const float* be1 = (const float*)d_in[8];
  const float* W2  = (const float*)d_in[9];
  const float* b2  = (const float*)d_in[10];
  const float* g2  = (const float*)d_in[11];
  const float* be2 = (const float*)d_in[12];
  float* out = (float*)d_out;

  // ws layout (~94.2 MB): bigmax(unused) | w3 | i3 | W1b | W2b | f2t | xpm | Hg
  // cv/cj alias the Hg region (Hg written only later, single stream => safe)
  char* ws = (char*)d_ws;
  float* w3            = (float*)(ws + 256);
  int*   i3            = (int*)  (ws + 786688);
  unsigned short* W1b  = (unsigned short*)(ws + 1573120);
  unsigned short* W2b  = (unsigned short*)(ws + 1769728);
  unsigned short* f2t  = (unsigned short*)(ws + 1900800);
  unsigned short* xpm  = (unsigned short*)(ws + 10289408);
  unsigned short* Hg   = (unsigned short*)(ws + 60621056);
  float* cv            = (float*)(ws + 60621056);            // aliases Hg[0 : 6.3MB)
  int*   cj            = (int*)  (ws + 60621056 + 6291456);  // aliases Hg[6.3 : 12.6MB)

  cvt_bf16_kernel<<<(HD*CIN + 255)/256, 256, 0, stream>>>(W1, W1b, HD*CIN);
  cvt_bf16_kernel<<<(HD*HD + 255)/256, 256, 0, stream>>>(W2, W2b, HD*HD);
  dim3 tb(32, 8);
  transpose_cn<<<dim3(SPT/32, C2D/32, BB), tb, 0, stream>>>(fea2, f2t, C2D, SPT, C2D);
  transpose_cn<<<dim3(NPT/32, C1D/32, BB), tb, 0, stream>>>(fea1, xpm, C1D, NPT, CIN);
  knn_part_kernel<<<dim3(NPT/256, BB, SPLIT), 256, 0, stream>>>(coor1, coor2, pad, cv, cj);
  knn_merge_kernel<<<BB*NPT/256, 256, 0, stream>>>(cv, cj, w3, i3);
  interp_kernel<<<BB*NPT/4, 256, 0, stream>>>(f2t, w3, i3, xpm);
  mlp1_kernel<<<BB*NPT/64, 256, 0, stream>>>(xpm, W1b, b1, g1, be1, Hg);
  mlp2_kernel<<<BB*NPT/64, 256, 0, stream>>>(Hg, W2b, b2, g2, be2, out);
}

// Round 5
// 285.979 us; speedup vs baseline: 1.2329x; 1.0092x over previous
//
#include <hip/hip_runtime.h>
#include <stdint.h>

#define BB 8
#define NPT 8192
#define SPT 2048
#define C1D 128
#define C2D 256
#define CIN 384
#define HD 256
#define SPLIT 8
#define SC (SPT/SPLIT)   // 256 source points per chunk

typedef __attribute__((ext_vector_type(8))) short bf16x8;
typedef __attribute__((ext_vector_type(4))) float f32x4;

__device__ __forceinline__ unsigned short f2b(float f){
  unsigned int u = __float_as_uint(f);
  u += 0x7fffu + ((u >> 16) & 1u);   // RNE; inputs finite
  return (unsigned short)(u >> 16);
}

// ---------------- f32 -> bf16 convert (for W1/W2 prep) ----------------
__global__ __launch_bounds__(256) void cvt_bf16_kernel(const float* __restrict__ src,
                                                       unsigned short* __restrict__ dst, int n){
  int i = blockIdx.x * 256 + threadIdx.x;
  if (i < n) dst[i] = f2b(src[i]);
}

// ---------------- pack source points: gs[b*SPT+s] = (x,y,z,|c|^2), padding applied ----------------
__global__ __launch_bounds__(256) void gsrc_kernel(const float* __restrict__ coor2,
    const unsigned char* __restrict__ pad, float4* __restrict__ gs){
  int i = blockIdx.x * 256 + threadIdx.x;      // i in [0, BB*SPT)
  int b = i >> 11, s = i & (SPT - 1);
  const float* cb = coor2 + b * 3 * SPT;
  float x = cb[s], y = cb[SPT + s], z = cb[2*SPT + s];
  if (pad[i]) { x = 1e19f; y = 1e19f; z = 1e19f; }
  float n2 = __fadd_rn(__fadd_rn(__fmul_rn(x,x), __fmul_rn(y,y)), __fmul_rn(z,z));
  gs[i] = make_float4(x, y, z, n2);
}

// ---------------- [B,C,N] f32 -> [B,N,C(dstStride)] bf16 tile transpose ----------------
__global__ __launch_bounds__(256) void transpose_cn(const float* __restrict__ src,
    unsigned short* __restrict__ dst, int Cdim, int Ndim, int dstStride){
  __shared__ unsigned short t[32][33];
  int b = blockIdx.z;
  int n0 = blockIdx.x * 32, c0 = blockIdx.y * 32;
  int tx = threadIdx.x, ty = threadIdx.y;
  const float* s = src + (size_t)b * Cdim * Ndim;
  unsigned short* d = dst + (size_t)b * Ndim * dstStride;
  #pragma unroll
  for (int i = 0; i < 4; i++)
    t[ty + i*8][tx] = f2b(s[(size_t)(c0 + ty + i*8) * Ndim + n0 + tx]);
  __syncthreads();
  #pragma unroll
  for (int i = 0; i < 4; i++)
    d[(size_t)(n0 + ty + i*8) * dstStride + c0 + tx] = t[tx][ty + i*8];
}

// ---------------- 3-NN partial scan over one S-chunk ----------------
// Source points come in via LOOP-UNIFORM global reads -> s_load into SGPRs
// (SMEM pipe, no LDS, no syncthreads). Zero LDS => 32 waves/CU occupancy.
// Distance math is bit-exact vs numpy: dot = fl(fl(fl(xx)+fl(yy))+fl(zz)),
// d = fma(-2,dot,fl(n1+n2)) == fl(fl(n1+n2) - fl(2*dot)).
__global__ __launch_bounds__(256) void knn_part_kernel(const float* __restrict__ coor1,
    const float4* __restrict__ gs, float* __restrict__ cv, int* __restrict__ cj){
  int b = blockIdx.y, c = blockIdx.z;
  int s0c = c * SC;
  const float4* gsb = gs + b * SPT + s0c;
  int n = blockIdx.x * 256 + threadIdx.x;
  const float* ca = coor1 + b * 3 * NPT;
  float x1 = ca[n], y1 = ca[NPT + n], z1 = ca[2*NPT + n];
  float n1 = __fadd_rn(__fadd_rn(__fmul_rn(x1,x1), __fmul_rn(y1,y1)), __fmul_rn(z1,z1));
  float v0 = 3.4e38f, v1 = 3.4e38f, v2 = 3.4e38f;
  int j0 = 0, j1 = 0, j2 = 0;
  #pragma unroll 8
  for (int s = 0; s < SC; s++){
    float4 q = gsb[s];                       // uniform address -> SGPR load
    float dot = __fadd_rn(__fadd_rn(__fmul_rn(x1,q.x), __fmul_rn(y1,q.y)), __fmul_rn(z1,q.z));
    float npn = __fadd_rn(n1, q.w);
    float d = __builtin_fmaf(-2.0f, dot, npn);
    bool l0 = d < v0, l1 = d < v1, l2 = d < v2;  // strict < keeps earliest index on ties
    j2 = l1 ? j1 : (l2 ? s : j2);
    j1 = l0 ? j0 : (l1 ? s : j1);
    j0 = l0 ? s  : j0;
    float nv2 = __builtin_amdgcn_fmed3f(v1, v2, d);
    float nv1 = __builtin_amdgcn_fmed3f(v0, v1, d);
    v0 = fminf(v0, d); v1 = nv1; v2 = nv2;
  }
  size_t m = (size_t)b * NPT + n;
  size_t base = (m * SPLIT + c) * 3;
  cv[base+0] = v0; cv[base+1] = v1; cv[base+2] = v2;
  cj[base+0] = s0c + j0; cj[base+1] = s0c + j1; cj[base+2] = s0c + j2;
}

// ---------------- merge SPLIT x top-3 -> global top-3 + weights ----------------
__global__ __launch_bounds__(256) void knn_merge_kernel(const float* __restrict__ cv,
    const int* __restrict__ cj, float* __restrict__ w3, int* __restrict__ i3){
  size_t m = (size_t)blockIdx.x * 256 + threadIdx.x;
  float v0 = 3.4e38f, v1 = 3.4e38f, v2 = 3.4e38f;
  int j0 = 0, j1 = 0, j2 = 0;
  // chunk-ascending insert order + strict < == global sequential scan tie-order
  #pragma unroll
  for (int c = 0; c < SPLIT; c++){
    #pragma unroll
    for (int k = 0; k < 3; k++){
      float d = cv[(m * SPLIT + c) * 3 + k];
      int j   = cj[(m * SPLIT + c) * 3 + k];
      bool l0 = d < v0, l1 = d < v1, l2 = d < v2;
      j2 = l1 ? j1 : (l2 ? j : j2);
      j1 = l0 ? j0 : (l1 ? j : j1);
      j0 = l0 ? j  : j0;
      float nv2 = __builtin_amdgcn_fmed3f(v1, v2, d);
      float nv1 = __builtin_amdgcn_fmed3f(v0, v1, d);
      v0 = fminf(v0, d); v1 = nv1; v2 = nv2;
    }
  }
  float r0 = 1.0f / fmaxf(v0, 1e-8f);
  float r1 = 1.0f / fmaxf(v1, 1e-8f);
  float r2 = 1.0f / fmaxf(v2, 1e-8f);
  float rs = (r0 + r1) + r2;
  w3[m*3+0] = r0 / rs; w3[m*3+1] = r1 / rs; w3[m*3+2] = r2 / rs;
  i3[m*3+0] = j0; i3[m*3+1] = j1; i3[m*3+2] = j2;
}

// ---------------- gather + weighted sum -> xpm[:,128:384] bf16 (wave per point) ----------------
__global__ __launch_bounds__(256) void interp_kernel(const unsigned short* __restrict__ f2t,
    const float* __restrict__ w3, const int* __restrict__ i3, unsigned short* __restrict__ xpm){
  int m = blockIdx.x * 4 + (threadIdx.x >> 6);
  int lane = threadIdx.x & 63;
  int b = m >> 13;
  int s0 = i3[m*3+0], s1 = i3[m*3+1], s2 = i3[m*3+2];
  float w0 = w3[m*3+0], w1 = w3[m*3+1], w2 = w3[m*3+2];
  const ushort4 a = *(const ushort4*)(f2t + (size_t)(b*SPT + s0) * C2D + lane*4);
  const ushort4 c = *(const ushort4*)(f2t + (size_t)(b*SPT + s1) * C2D + lane*4);
  const ushort4 e = *(const ushort4*)(f2t + (size_t)(b*SPT + s2) * C2D + lane*4);
  #define B2F(u) __uint_as_float(((unsigned int)(u)) << 16)
  ushort4 o;
  o.x = f2b(w0*B2F(a.x) + w1*B2F(c.x) + w2*B2F(e.x));
  o.y = f2b(w0*B2F(a.y) + w1*B2F(c.y) + w2*B2F(e.y));
  o.z = f2b(w0*B2F(a.z) + w1*B2F(c.z) + w2*B2F(e.z));
  o.w = f2b(w0*B2F(a.w) + w1*B2F(c.w) + w2*B2F(e.w));
  *(ushort4*)(xpm + (size_t)m * CIN + C1D + lane*4) = o;
}

// ---------------- GEMM1 (K=384, bf16 MFMA) + bias + LN + relu -> Hg bf16 [m][256] ----------------
// block: 256 thr = 4 waves, 64 points; wave w owns points m0+w*16+(lane&15), all 256 outs.
__global__ __launch_bounds__(256) void mlp1_kernel(const unsigned short* __restrict__ xpm,
    const unsigned short* __restrict__ Wg, const float* __restrict__ bg,
    const float* __restrict__ gg, const float* __restrict__ beg,
    unsigned short* __restrict__ Hg){
  __shared__ __align__(16) unsigned short Ws[256*40];   // W chunk [256 o][32 k], pad->40
  __shared__ __align__(16) unsigned short Xs[64*40];    // X chunk [64 m][32 k]
  __shared__ __align__(16) unsigned short Hb[64*136];   // store bounce, 128 cols + pad
  __shared__ float sB[256], sG[256], sBe[256];
  int tid = threadIdx.x;
  int m0 = blockIdx.x * 64;
  sB[tid] = bg[tid]; sG[tid] = gg[tid]; sBe[tid] = beg[tid];
  int w = tid >> 6, lane = tid & 63, col = lane & 15, quad = lane >> 4;
  f32x4 acc[16];
  #pragma unroll
  for (int i = 0; i < 16; i++) acc[i] = (f32x4)0.0f;
  for (int kb = 0; kb < CIN; kb += 32){
    __syncthreads();
    {
      const int4* s4 = (const int4*)(Wg + (size_t)tid * CIN + kb);
      int4* d4 = (int4*)(Ws + tid * 40);
      #pragma unroll
      for (int i = 0; i < 4; i++) d4[i] = s4[i];
    }
    {
      int mr = tid >> 2, part = tid & 3;
      *(int4*)(Xs + mr*40 + part*8) = *(const int4*)(xpm + (size_t)(m0 + mr) * CIN + kb + part*8);
    }
    __syncthreads();
    bf16x8 bfrag = *(const bf16x8*)(Xs + (w*16 + col)*40 + quad*8);
    #pragma unroll
    for (int ot = 0; ot < 16; ot++){
      bf16x8 afrag = *(const bf16x8*)(Ws + (ot*16 + col)*40 + quad*8);
      acc[ot] = __builtin_amdgcn_mfma_f32_16x16x32_bf16(afrag, bfrag, acc[ot], 0, 0, 0);
    }
  }
  float s1 = 0.f, s2 = 0.f;
  #pragma unroll
  for (int ot = 0; ot < 16; ot++)
    #pragma unroll
    for (int r = 0; r < 4; r++){
      int o = ot*16 + quad*4 + r;
      float v = acc[ot][r] + sB[o];
      acc[ot][r] = v;
      s1 += v; s2 += v*v;
    }
  s1 += __shfl_xor(s1, 16); s1 += __shfl_xor(s1, 32);
  s2 += __shfl_xor(s2, 16); s2 += __shfl_xor(s2, 32);
  float mu = s1 * (1.f/256.f);
  float rinv = rsqrtf(s2 * (1.f/256.f) - mu*mu + 1e-5f);
  for (int half = 0; half < 2; half++){
    __syncthreads();
    #pragma unroll
    for (int ot8 = 0; ot8 < 8; ot8++){
      int ot = half*8 + ot8;
      int ob = ot*16 + quad*4;
      ushort4 hv;
      hv.x = f2b(fmaxf((acc[ot][0] - mu) * rinv * sG[ob+0] + sBe[ob+0], 0.f));
      hv.y = f2b(fmaxf((acc[ot][1] - mu) * rinv * sG[ob+1] + sBe[ob+1], 0.f));
      hv.z = f2b(fmaxf((acc[ot][2] - mu) * rinv * sG[ob+2] + sBe[ob+2], 0.f));
      hv.w = f2b(fmaxf((acc[ot][3] - mu) * rinv * sG[ob+3] + sBe[ob+3], 0.f));
      *(ushort4*)(Hb + (w*16 + col)*136 + ot8*16 + quad*4) = hv;
    }
    __syncthreads();
    int mr = tid >> 2, part = tid & 3;
    #pragma unroll
    for (int r = 0; r < 4; r++){
      int piece = part*4 + r;
      *(int4*)(Hg + (size_t)(m0 + mr)*HD + half*128 + piece*8) = *(const int4*)(Hb + mr*136 + piece*8);
    }
  }
}

// ---------------- GEMM2 (K=256, bf16 MFMA) + bias + LN + relu -> out f32 [B,256,N] ----------------
__global__ __launch_bounds__(256) void mlp2_kernel(const unsigned short* __restrict__ Hg,
    const unsigned short* __restrict__ Wg, const float* __restrict__ bg,
    const float* __restrict__ gg, const float* __restrict__ beg,
    float* __restrict__ outg){
  __shared__ __align__(16) unsigned short Ws[256*40];
  __shared__ __align__(16) unsigned short Xs[64*40];
  __shared__ float sB[256], sG[256], sBe[256];
  int tid = threadIdx.x;
  int m0 = blockIdx.x * 64;
  int b = m0 >> 13, n0 = m0 & (NPT - 1);
  sB[tid] = bg[tid]; sG[tid] = gg[tid]; sBe[tid] = beg[tid];
  int w = tid >> 6, lane = tid & 63, col = lane & 15, quad = lane >> 4;
  f32x4 acc[16];
  #pragma unroll
  for (int i = 0; i < 16; i++) acc[i] = (f32x4)0.0f;
  for (int kb = 0; kb < HD; kb += 32){
    __syncthreads();
    {
      const int4* s4 = (const int4*)(Wg + (size_t)tid * HD + kb);
      int4* d4 = (int4*)(Ws + tid * 40);
      #pragma unroll
      for (int i = 0; i < 4; i++) d4[i] = s4[i];
    }
    {
      int mr = tid >> 2, part = tid & 3;
      *(int4*)(Xs + mr*40 + part*8) = *(const int4*)(Hg + (size_t)(m0 + mr) * HD + kb + part*8);
    }
    __syncthreads();
    bf16x8 bfrag = *(const bf16x8*)(Xs + (w*16 + col)*40 + quad*8);
    #pragma unroll
    for (int ot = 0; ot < 16; ot++){
      bf16x8 afrag = *(const bf16x8*)(Ws + (ot*16 + col)*40 + quad*8);
      acc[ot] = __builtin_amdgcn_mfma_f32_16x16x32_bf16(afrag, bfrag, acc[ot], 0, 0, 0);
    }
  }
  float s1 = 0.f, s2 = 0.f;
  #pragma unroll
  for (int ot = 0; ot < 16; ot++)
    #pragma unroll
    for (int r = 0; r < 4; r++){
      int o = ot*16 + quad*4 + r;
      float v = acc[ot][r] + sB[o];
      acc[ot][r] = v;
      s1 += v; s2 += v*v;
    }
  s1 += __shfl_xor(s1, 16); s1 += __shfl_xor(s1, 32);
  s2 += __shfl_xor(s2, 16); s2 += __shfl_xor(s2, 32);
  float mu = s1 * (1.f/256.f);
  float rinv = rsqrtf(s2 * (1.f/256.f) - mu*mu + 1e-5f);
  size_t obase = (size_t)b * HD * NPT + n0 + w*16 + col;
  #pragma unroll
  for (int ot = 0; ot < 16; ot++)
    #pragma unroll
    for (int r = 0; r < 4; r++){
      int o = ot*16 + quad*4 + r;
      float v = (acc[ot][r] - mu) * rinv * sG[o] + sBe[o];
      outg[obase + (size_t)o * NPT] = fmaxf(v, 0.f);
    }
}

extern "C" void kernel_launch(void* const* d_in, const int* in_sizes, int n_in,
                              void* d_out, int out_size, void* d_ws, size_t ws_size,
                              hipStream_t stream){
  const float* coor1 = (const float*)d_in[0];
  const float* coor2 = (const float*)d_in[1];
  const float* fea1  = (const float*)d_in[2];
  const float* fea2  = (const float*)d_in[3];
  const unsigned char* pad = (const unsigned char*)d_in[4];
  const float* W1  = (const float*)d_in[5];
  const float* b1  = (const float*)d_in[6];
  const float* g1  = (const float*)d_in[7];
  const float* be1 = (const float*)d_in[8];
  const float* W2  = (const float*)d_in[9];
  const float* b2  = (const float*)d_in[10];
  const float* g2  = (const float*)d_in[11];
  const float* be2 = (const float*)d_in[12];
  float* out = (float*)d_out;

  // ws layout (~94.2 MB, same proven footprint): | w3 | i3 | W1b | W2b | f2t | xpm | Hg
  // cv/cj/gs alias the Hg region (Hg written only later, single stream => safe)
  char* ws = (char*)d_ws;
  float* w3            = (float*)(ws + 256);
  int*   i3            = (int*)  (ws + 786688);
  unsigned short* W1b  = (unsigned short*)(ws + 1573120);
  unsigned short* W2b  = (unsigned short*)(ws + 1769728);
  unsigned short* f2t  = (unsigned short*)(ws + 1900800);
  unsigned short* xpm  = (unsigned short*)(ws + 10289408);
  unsigned short* Hg   = (unsigned short*)(ws + 60621056);
  float* cv            = (float*)(ws + 60621056);             // aliases Hg[0 : 6.3MB)
  int*   cj            = (int*)  (ws + 60621056 + 6291456);   // aliases Hg[6.3 : 12.6MB)
  float4* gs           = (float4*)(ws + 60621056 + 16777216); // aliases Hg[16 : 16.25MB)

  cvt_bf16_kernel<<<(HD*CIN + 255)/256, 256, 0, stream>>>(W1, W1b, HD*CIN);
  cvt_bf16_kernel<<<(HD*HD + 255)/256, 256, 0, stream>>>(W2, W2b, HD*HD);
  gsrc_kernel<<<BB*SPT/256, 256, 0, stream>>>(coor2, pad, gs);
  dim3 tb(32, 8);
  transpose_cn<<<dim3(SPT/32, C2D/32, BB), tb, 0, stream>>>(fea2, f2t, C2D, SPT, C2D);
  transpose_cn<<<dim3(NPT/32, C1D/32, BB), tb, 0, stream>>>(fea1, xpm, C1D, NPT, CIN);
  knn_part_kernel<<<dim3(NPT/256, BB, SPLIT), 256, 0, stream>>>(coor1, gs, cv, cj);
  knn_merge_kernel<<<BB*NPT/256, 256, 0, stream>>>(cv, cj, w3, i3);
  interp_kernel<<<BB*NPT/4, 256, 0, stream>>>(f2t, w3, i3, xpm);
  mlp1_kernel<<<BB*NPT/64, 256, 0, stream>>>(xpm, W1b, b1, g1, be1, Hg);
  mlp2_kernel<<<BB*NPT/64, 256, 0, stream>>>(Hg, W2b, b2, g2, be2, out);
}